// Round 14
// baseline (314.530 us; speedup 1.0000x reference)
//
#include <hip/hip_runtime.h>
#include <hip/hip_fp16.h>

#define H 64
#define CBS 512           // nodes per coarse bucket
#define CB_BITS 9
#define TILE 8192         // edges per partition tile
#define CAP 9216          // slab capacity per bucket

typedef _Float16 f16;
typedef __attribute__((ext_vector_type(2))) _Float16 v2h;
typedef __attribute__((ext_vector_type(8))) _Float16 v8h;
typedef __attribute__((ext_vector_type(4))) float v4f;

// ---------------------------------------------------------------------------
// Init: zero BN stats, seed slab cursors.
// ---------------------------------------------------------------------------
__global__ void init_kernel(float* __restrict__ stats, int* __restrict__ gcursor, int CB) {
    int t = blockIdx.x * blockDim.x + threadIdx.x;
    if (t < 128) stats[t] = 0.f;
    if (t < CB) gcursor[t * 16] = t * CAP;
}

// x (fp32) -> xh (fp16), vectorized.
__global__ __launch_bounds__(256)
void cvt_x_kernel(const float* __restrict__ x, f16* __restrict__ xh, int total4) {
    int i = blockIdx.x * blockDim.x + threadIdx.x;
    if (i >= total4) return;
    float4 v = ((const float4*)x)[i];
    f16 h0 = (f16)v.x, h1 = (f16)v.y, h2 = (f16)v.z, h3 = (f16)v.w;
    ushort4 pk;
    pk.x = *(unsigned short*)&h0; pk.y = *(unsigned short*)&h1;
    pk.z = *(unsigned short*)&h2; pk.w = *(unsigned short*)&h3;
    ((ushort4*)xh)[i] = pk;
}

// ---------------------------------------------------------------------------
// LDS-staged multi-split partition into per-bucket slabs (R11-proven).
// ---------------------------------------------------------------------------
__global__ __launch_bounds__(256)
void part_staged_kernel(const int* __restrict__ ei, int* __restrict__ gcursor,
                        int* __restrict__ pairs, int E, int N, int CB) {
    __shared__ int sd[256];
    __shared__ int excl[256];
    __shared__ int gbase[256];
    __shared__ int lcur[256];
    __shared__ int stage[TILE];
    __shared__ unsigned char bin8[TILE];
    int t = threadIdx.x;
    int ntiles = (E + TILE - 1) / TILE;
    for (int tile = blockIdx.x; tile < ntiles; tile += gridDim.x) {
        int base = tile * TILE;
        int cnt = min(TILE, E - base);
        sd[t] = 0;
        __syncthreads();
        for (int i = t; i < cnt; i += 256) {
            int s = ei[base + i];
            int d = ei[E + base + i];
            if ((unsigned)s < (unsigned)N && (unsigned)d < (unsigned)N)
                atomicAdd(&sd[d >> CB_BITS], 1);
        }
        __syncthreads();
        int v = sd[t];
        __syncthreads();
        for (int off = 1; off < 256; off <<= 1) {
            int add = (t >= off) ? sd[t - off] : 0;
            __syncthreads();
            sd[t] += add;
            __syncthreads();
        }
        int ex = sd[t] - v;
        excl[t] = ex;
        lcur[t] = ex;
        if (t < CB && v > 0) gbase[t] = atomicAdd(&gcursor[t * 16], v);
        int tot = sd[255];
        __syncthreads();
        for (int i = t; i < cnt; i += 256) {
            int s = ei[base + i];
            int d = ei[E + base + i];
            if ((unsigned)s < (unsigned)N && (unsigned)d < (unsigned)N) {
                int cb = d >> CB_BITS;
                int pos = atomicAdd(&lcur[cb], 1);
                stage[pos] = s | ((d & (CBS - 1)) << 17);
                bin8[pos] = (unsigned char)cb;
            }
        }
        __syncthreads();
        for (int i = t; i < tot; i += 256) {
            int b8 = bin8[i];
            pairs[gbase[b8] + (i - excl[b8])] = stage[i];
        }
        __syncthreads();
    }
}

__global__ __launch_bounds__(256)
void scan_cb_kernel(const int* __restrict__ gcursor, int* __restrict__ gbb,
                    int* __restrict__ rowptr, int CB, int N) {
    __shared__ int sd[256];
    int t = threadIdx.x;
    int cnt = (t < CB) ? (gcursor[t * 16] - t * CAP) : 0;
    sd[t] = cnt; __syncthreads();
    for (int off = 1; off < 256; off <<= 1) {
        int add = (t >= off) ? sd[t - off] : 0;
        __syncthreads();
        sd[t] += add;
        __syncthreads();
    }
    if (t < CB) gbb[t] = sd[t] - cnt;
    if (t == 0) { gbb[CB] = sd[255]; rowptr[N] = sd[255]; }
}

__global__ __launch_bounds__(256)
void bucket_csr_kernel(const int* __restrict__ pairs, const int* __restrict__ gcursor,
                       const int* __restrict__ gbb,
                       int* __restrict__ ebuf, int* __restrict__ rowptr, int N) {
    __shared__ int hist[CBS];
    __shared__ int cur[CBS];
    __shared__ int sd[256];
    __shared__ int carry_s;
    int b = blockIdx.x;
    int t = threadIdx.x;
    int pb = b * CAP;
    int cnt = gcursor[b * 16] - pb;
    int gb = gbb[b];
    for (int i = t; i < CBS; i += 256) hist[i] = 0;
    if (t == 0) carry_s = 0;
    __syncthreads();
    for (int i = t; i < cnt; i += 256)
        atomicAdd(&hist[(pairs[pb + i] >> 17) & (CBS - 1)], 1);
    __syncthreads();
    for (int start = 0; start < CBS; start += 256) {
        int v = hist[start + t];
        sd[t] = v; __syncthreads();
        for (int off = 1; off < 256; off <<= 1) {
            int add = (t >= off) ? sd[t - off] : 0;
            __syncthreads();
            sd[t] += add;
            __syncthreads();
        }
        int ex = sd[t] - v + carry_s;
        cur[start + t] = ex;
        int node = b * CBS + start + t;
        if (node < N) rowptr[node] = gb + ex;
        __syncthreads();
        if (t == 0) carry_s += sd[255];
        __syncthreads();
    }
    for (int i = t; i < cnt; i += 256) {
        int p = pairs[pb + i];
        int pos = atomicAdd(&cur[(p >> 17) & (CBS - 1)], 1);
        ebuf[gb + pos] = p & 0x1FFFF;
    }
}

// ---------------------------------------------------------------------------
// Fold linear head (fp32):  (relu(z)@W2b + b2b)@LW + LB == relu(z)@Wf + bf
// ---------------------------------------------------------------------------
__global__ void fold_head_kernel(const float* __restrict__ W2b, const float* __restrict__ B2b,
                                 const float* __restrict__ LW, const float* __restrict__ LB,
                                 float* __restrict__ Wf, float* __restrict__ bf) {
    int t = blockIdx.x * blockDim.x + threadIdx.x;
    if (t < 640) {
        int k = t / 10, c = t % 10;
        float a = 0.f;
        for (int m = 0; m < H; ++m) a = fmaf(W2b[k * H + m], LW[m * 10 + c], a);
        Wf[t] = a;
    } else if (t < 650) {
        int c = t - 640;
        float a = LB[c];
        for (int m = 0; m < H; ++m) a = fmaf(B2b[m], LW[m * 10 + c], a);
        bf[c] = a;
    }
}

// ---------------------------------------------------------------------------
// Repack weights into fp16 MFMA B-fragment order (R13-proven).
// ---------------------------------------------------------------------------
__global__ void repack_kernel(const float* __restrict__ W1a, const float* __restrict__ W1b,
                              const float* __restrict__ W2a, const float* __restrict__ Wf,
                              f16* __restrict__ pk1a, f16* __restrict__ pk1b,
                              f16* __restrict__ pk2a, f16* __restrict__ pkf) {
    int t = blockIdx.x * blockDim.x + threadIdx.x;
    if (t < 12288) {
        int m = t >> 12;
        int e = t & 4095;
        int j = e & 7, lane = (e >> 3) & 63, ks = (e >> 9) & 1, nt = e >> 10;
        int row = ks * 32 + ((lane >> 4) & 3) * 8 + j;
        int col = nt * 16 + (lane & 15);
        const float* W = (m == 0) ? W1a : (m == 1) ? W1b : W2a;
        f16* P = (m == 0) ? pk1a : (m == 1) ? pk1b : pk2a;
        P[e] = (f16)W[row * 64 + col];
    } else if (t < 13312) {
        int e = t - 12288;
        int j = e & 7, lane = (e >> 3) & 63, ks = e >> 9;
        int row = ks * 32 + ((lane >> 4) & 3) * 8 + j;
        int col = lane & 15;
        pkf[e] = (col < 10) ? (f16)Wf[row * 10 + col] : (f16)0;
    }
}

// ---------------------------------------------------------------------------
// Layer-1 gather, DUAL-EDGE: wave handles 2 edges per row-load round.
// lane = (half, fpair): half = lane>>5 picks edge p+2i+half; fpair = lane&31
// covers features {2*fpair, 2*fpair+1} via one 4B v2h load (32 lanes = 128B
// row). Edge indices are wave-uniform s_loads + per-half select. Self row
// counted in half 0 only; halves combined by shfl_xor(32) at the end.
// ---------------------------------------------------------------------------
__global__ __launch_bounds__(256)
void gather1_kernel(const f16* __restrict__ xh, const int* __restrict__ rowptr,
                    const int* __restrict__ ebuf, f16* __restrict__ bufA, int N) {
    int wid = (int)(((long long)blockIdx.x * blockDim.x + threadIdx.x) >> 6);
    int lane = threadIdx.x & 63;
    if (wid >= N) return;
    int half = lane >> 5;
    int fp = lane & 31;
    int p0 = __builtin_amdgcn_readfirstlane(rowptr[wid]);
    int pe = __builtin_amdgcn_readfirstlane(rowptr[wid + 1]);
    float a0 = 0.f, a1 = 0.f;
    if (half == 0) {
        v2h sv = *(const v2h*)(xh + ((size_t)wid << 6) + (fp << 1));
        a0 = (float)sv[0]; a1 = (float)sv[1];
    }
    int p = p0;
    for (; p + 16 <= pe; p += 16) {
        int s0 = half ? ebuf[p + 1]  : ebuf[p + 0];
        int s1 = half ? ebuf[p + 3]  : ebuf[p + 2];
        int s2 = half ? ebuf[p + 5]  : ebuf[p + 4];
        int s3 = half ? ebuf[p + 7]  : ebuf[p + 6];
        int s4 = half ? ebuf[p + 9]  : ebuf[p + 8];
        int s5 = half ? ebuf[p + 11] : ebuf[p + 10];
        int s6 = half ? ebuf[p + 13] : ebuf[p + 12];
        int s7 = half ? ebuf[p + 15] : ebuf[p + 14];
        v2h w0 = *(const v2h*)(xh + ((size_t)s0 << 6) + (fp << 1));
        v2h w1 = *(const v2h*)(xh + ((size_t)s1 << 6) + (fp << 1));
        v2h w2 = *(const v2h*)(xh + ((size_t)s2 << 6) + (fp << 1));
        v2h w3 = *(const v2h*)(xh + ((size_t)s3 << 6) + (fp << 1));
        v2h w4 = *(const v2h*)(xh + ((size_t)s4 << 6) + (fp << 1));
        v2h w5 = *(const v2h*)(xh + ((size_t)s5 << 6) + (fp << 1));
        v2h w6 = *(const v2h*)(xh + ((size_t)s6 << 6) + (fp << 1));
        v2h w7 = *(const v2h*)(xh + ((size_t)s7 << 6) + (fp << 1));
        a0 += (((float)w0[0] + (float)w1[0]) + ((float)w2[0] + (float)w3[0]))
            + (((float)w4[0] + (float)w5[0]) + ((float)w6[0] + (float)w7[0]));
        a1 += (((float)w0[1] + (float)w1[1]) + ((float)w2[1] + (float)w3[1]))
            + (((float)w4[1] + (float)w5[1]) + ((float)w6[1] + (float)w7[1]));
    }
    if (p + 8 <= pe) {
        int s0 = half ? ebuf[p + 1] : ebuf[p + 0];
        int s1 = half ? ebuf[p + 3] : ebuf[p + 2];
        int s2 = half ? ebuf[p + 5] : ebuf[p + 4];
        int s3 = half ? ebuf[p + 7] : ebuf[p + 6];
        v2h w0 = *(const v2h*)(xh + ((size_t)s0 << 6) + (fp << 1));
        v2h w1 = *(const v2h*)(xh + ((size_t)s1 << 6) + (fp << 1));
        v2h w2 = *(const v2h*)(xh + ((size_t)s2 << 6) + (fp << 1));
        v2h w3 = *(const v2h*)(xh + ((size_t)s3 << 6) + (fp << 1));
        a0 += ((float)w0[0] + (float)w1[0]) + ((float)w2[0] + (float)w3[0]);
        a1 += ((float)w0[1] + (float)w1[1]) + ((float)w2[1] + (float)w3[1]);
        p += 8;
    }
    for (; p < pe; p += 2) {
        int idx = p + half;
        if (idx < pe) {
            int s = ebuf[idx];
            v2h w = *(const v2h*)(xh + ((size_t)s << 6) + (fp << 1));
            a0 += (float)w[0];
            a1 += (float)w[1];
        }
    }
    a0 += __shfl_xor(a0, 32);
    a1 += __shfl_xor(a1, 32);
    if (half == 0) {
        v2h o;
        o[0] = (f16)a0; o[1] = (f16)a1;
        *(v2h*)(bufA + ((size_t)wid << 6) + (fp << 1)) = o;
    }
}

// ---------------------------------------------------------------------------
// Layer-2 gather, dual-edge, with self term and full folded BN:
//   bufC = scale*(h1[self] + sum_j h1[j]) + (deg+1)*shift      (fp16 out)
// ---------------------------------------------------------------------------
__global__ __launch_bounds__(256)
void gather2_kernel(const f16* __restrict__ h1p, const float* __restrict__ scale,
                    const float* __restrict__ shiftv, const int* __restrict__ rowptr,
                    const int* __restrict__ ebuf, f16* __restrict__ bufC, int N) {
    int wid = (int)(((long long)blockIdx.x * blockDim.x + threadIdx.x) >> 6);
    int lane = threadIdx.x & 63;
    if (wid >= N) return;
    int half = lane >> 5;
    int fp = lane & 31;
    int p0 = __builtin_amdgcn_readfirstlane(rowptr[wid]);
    int pe = __builtin_amdgcn_readfirstlane(rowptr[wid + 1]);
    float a0 = 0.f, a1 = 0.f;
    if (half == 0) {
        v2h sv = *(const v2h*)(h1p + ((size_t)wid << 6) + (fp << 1));
        a0 = (float)sv[0]; a1 = (float)sv[1];
    }
    int p = p0;
    for (; p + 16 <= pe; p += 16) {
        int s0 = half ? ebuf[p + 1]  : ebuf[p + 0];
        int s1 = half ? ebuf[p + 3]  : ebuf[p + 2];
        int s2 = half ? ebuf[p + 5]  : ebuf[p + 4];
        int s3 = half ? ebuf[p + 7]  : ebuf[p + 6];
        int s4 = half ? ebuf[p + 9]  : ebuf[p + 8];
        int s5 = half ? ebuf[p + 11] : ebuf[p + 10];
        int s6 = half ? ebuf[p + 13] : ebuf[p + 12];
        int s7 = half ? ebuf[p + 15] : ebuf[p + 14];
        v2h w0 = *(const v2h*)(h1p + ((size_t)s0 << 6) + (fp << 1));
        v2h w1 = *(const v2h*)(h1p + ((size_t)s1 << 6) + (fp << 1));
        v2h w2 = *(const v2h*)(h1p + ((size_t)s2 << 6) + (fp << 1));
        v2h w3 = *(const v2h*)(h1p + ((size_t)s3 << 6) + (fp << 1));
        v2h w4 = *(const v2h*)(h1p + ((size_t)s4 << 6) + (fp << 1));
        v2h w5 = *(const v2h*)(h1p + ((size_t)s5 << 6) + (fp << 1));
        v2h w6 = *(const v2h*)(h1p + ((size_t)s6 << 6) + (fp << 1));
        v2h w7 = *(const v2h*)(h1p + ((size_t)s7 << 6) + (fp << 1));
        a0 += (((float)w0[0] + (float)w1[0]) + ((float)w2[0] + (float)w3[0]))
            + (((float)w4[0] + (float)w5[0]) + ((float)w6[0] + (float)w7[0]));
        a1 += (((float)w0[1] + (float)w1[1]) + ((float)w2[1] + (float)w3[1]))
            + (((float)w4[1] + (float)w5[1]) + ((float)w6[1] + (float)w7[1]));
    }
    if (p + 8 <= pe) {
        int s0 = half ? ebuf[p + 1] : ebuf[p + 0];
        int s1 = half ? ebuf[p + 3] : ebuf[p + 2];
        int s2 = half ? ebuf[p + 5] : ebuf[p + 4];
        int s3 = half ? ebuf[p + 7] : ebuf[p + 6];
        v2h w0 = *(const v2h*)(h1p + ((size_t)s0 << 6) + (fp << 1));
        v2h w1 = *(const v2h*)(h1p + ((size_t)s1 << 6) + (fp << 1));
        v2h w2 = *(const v2h*)(h1p + ((size_t)s2 << 6) + (fp << 1));
        v2h w3 = *(const v2h*)(h1p + ((size_t)s3 << 6) + (fp << 1));
        a0 += ((float)w0[0] + (float)w1[0]) + ((float)w2[0] + (float)w3[0]);
        a1 += ((float)w0[1] + (float)w1[1]) + ((float)w2[1] + (float)w3[1]);
        p += 8;
    }
    for (; p < pe; p += 2) {
        int idx = p + half;
        if (idx < pe) {
            int s = ebuf[idx];
            v2h w = *(const v2h*)(h1p + ((size_t)s << 6) + (fp << 1));
            a0 += (float)w[0];
            a1 += (float)w[1];
        }
    }
    a0 += __shfl_xor(a0, 32);
    a1 += __shfl_xor(a1, 32);
    if (half == 0) {
        float degp1 = (float)(pe - p0 + 1);
        int f0 = fp << 1;
        v2h o;
        o[0] = (f16)(a0 * scale[f0] + degp1 * shiftv[f0]);
        o[1] = (f16)(a1 * scale[f0 + 1] + degp1 * shiftv[f0 + 1]);
        *(v2h*)(bufC + ((size_t)wid << 6) + f0) = o;
    }
}

// ---------------------------------------------------------------------------
// MFMA MLP layer 1 + fused BN stats (R13-proven).
// ---------------------------------------------------------------------------
__global__ __launch_bounds__(256)
void mlp1_kernel(const f16* __restrict__ bufA, f16* __restrict__ h1p,
                 const f16* __restrict__ pk1a, const f16* __restrict__ pk1b,
                 const float* __restrict__ B1a, const float* __restrict__ B1b,
                 float* __restrict__ stats, int N) {
    __shared__ f16 Su[4][16 * 72];
    __shared__ f16 Sh[4][16 * 72];
    __shared__ float red[2][4][64];
    int t = threadIdx.x, wv = t >> 6, lane = t & 63;
    int quad = lane >> 4, r16 = lane & 15;
    int node0 = blockIdx.x * 64 + wv * 16;
    int nodeA = node0 + r16;

    v8h a0 = {}, a1 = {};
    if (nodeA < N) {
        a0 = *(const v8h*)(bufA + (size_t)nodeA * 64 + quad * 8);
        a1 = *(const v8h*)(bufA + (size_t)nodeA * 64 + 32 + quad * 8);
    }
#pragma unroll
    for (int nt = 0; nt < 4; ++nt) {
        v8h b0 = *(const v8h*)(pk1a + (((nt * 2 + 0) * 64 + lane) << 3));
        v8h b1 = *(const v8h*)(pk1a + (((nt * 2 + 1) * 64 + lane) << 3));
        v4f c = {0.f, 0.f, 0.f, 0.f};
        c = __builtin_amdgcn_mfma_f32_16x16x32_f16(a0, b0, c, 0, 0, 0);
        c = __builtin_amdgcn_mfma_f32_16x16x32_f16(a1, b1, c, 0, 0, 0);
        float bias = B1a[nt * 16 + r16];
#pragma unroll
        for (int reg = 0; reg < 4; ++reg)
            Su[wv][(quad * 4 + reg) * 72 + nt * 16 + r16] = (f16)fmaxf(c[reg] + bias, 0.f);
    }
    __syncthreads();
    v8h u0 = *(const v8h*)(&Su[wv][r16 * 72 + quad * 8]);
    v8h u1 = *(const v8h*)(&Su[wv][r16 * 72 + 32 + quad * 8]);
#pragma unroll
    for (int nt = 0; nt < 4; ++nt) {
        v8h b0 = *(const v8h*)(pk1b + (((nt * 2 + 0) * 64 + lane) << 3));
        v8h b1 = *(const v8h*)(pk1b + (((nt * 2 + 1) * 64 + lane) << 3));
        v4f c = {0.f, 0.f, 0.f, 0.f};
        c = __builtin_amdgcn_mfma_f32_16x16x32_f16(u0, b0, c, 0, 0, 0);
        c = __builtin_amdgcn_mfma_f32_16x16x32_f16(u1, b1, c, 0, 0, 0);
        float bias = B1b[nt * 16 + r16];
#pragma unroll
        for (int reg = 0; reg < 4; ++reg) {
            int row = quad * 4 + reg;
            bool valid = (node0 + row) < N;
            Sh[wv][row * 72 + nt * 16 + r16] = valid ? (f16)(c[reg] + bias) : (f16)0;
        }
    }
    __syncthreads();
    for (int i = lane; i < 1024; i += 64) {
        int row = i >> 6, col = i & 63;
        int node = node0 + row;
        if (node < N) h1p[(size_t)node * 64 + col] = Sh[wv][row * 72 + col];
    }
    float s = 0.f, s2 = 0.f;
#pragma unroll
    for (int row = 0; row < 16; ++row) {
        float v = (float)Sh[wv][row * 72 + lane];
        s += v;
        s2 = fmaf(v, v, s2);
    }
    red[0][wv][lane] = s;
    red[1][wv][lane] = s2;
    __syncthreads();
    if (wv == 0) {
        float ts  = (red[0][0][lane] + red[0][1][lane]) + (red[0][2][lane] + red[0][3][lane]);
        float ts2 = (red[1][0][lane] + red[1][1][lane]) + (red[1][2][lane] + red[1][3][lane]);
        unsafeAtomicAdd(&stats[lane], ts);
        unsafeAtomicAdd(&stats[64 + lane], ts2);
    }
}

__global__ void bn_finalize_kernel(const float* __restrict__ stats,
                                   const float* __restrict__ gamma,
                                   const float* __restrict__ beta,
                                   float* __restrict__ scale, float* __restrict__ shiftv, float n) {
    int f = threadIdx.x;
    if (f >= H) return;
    float mean = stats[f] / n;
    float var = stats[H + f] / n - mean * mean;   // biased, matches jnp.var
    var = fmaxf(var, 0.f);
    float s = gamma[f] * rsqrtf(var + 1e-5f);
    scale[f] = s;
    shiftv[f] = beta[f] - mean * s;
}

// ---------------------------------------------------------------------------
// MFMA MLP layer 2 + folded head (R13-proven).
// ---------------------------------------------------------------------------
__global__ __launch_bounds__(256)
void mlp2_kernel(const f16* __restrict__ bufC,
                 const f16* __restrict__ pk2a, const f16* __restrict__ pkf,
                 const float* __restrict__ B2a, const float* __restrict__ bf,
                 float* __restrict__ out, int N) {
    __shared__ f16 Su[4][16 * 72];
    int t = threadIdx.x, wv = t >> 6, lane = t & 63;
    int quad = lane >> 4, r16 = lane & 15;
    int node0 = blockIdx.x * 64 + wv * 16;
    int nodeA = node0 + r16;

    v8h a0 = {}, a1 = {};
    if (nodeA < N) {
        a0 = *(const v8h*)(bufC + (size_t)nodeA * 64 + quad * 8);
        a1 = *(const v8h*)(bufC + (size_t)nodeA * 64 + 32 + quad * 8);
    }
#pragma unroll
    for (int nt = 0; nt < 4; ++nt) {
        v8h b0 = *(const v8h*)(pk2a + (((nt * 2 + 0) * 64 + lane) << 3));
        v8h b1 = *(const v8h*)(pk2a + (((nt * 2 + 1) * 64 + lane) << 3));
        v4f c = {0.f, 0.f, 0.f, 0.f};
        c = __builtin_amdgcn_mfma_f32_16x16x32_f16(a0, b0, c, 0, 0, 0);
        c = __builtin_amdgcn_mfma_f32_16x16x32_f16(a1, b1, c, 0, 0, 0);
        float bias = B2a[nt * 16 + r16];
#pragma unroll
        for (int reg = 0; reg < 4; ++reg)
            Su[wv][(quad * 4 + reg) * 72 + nt * 16 + r16] = (f16)fmaxf(c[reg] + bias, 0.f);
    }
    __syncthreads();
    v8h u0 = *(const v8h*)(&Su[wv][r16 * 72 + quad * 8]);
    v8h u1 = *(const v8h*)(&Su[wv][r16 * 72 + 32 + quad * 8]);
    v8h b0 = *(const v8h*)(pkf + ((0 * 64 + lane) << 3));
    v8h b1 = *(const v8h*)(pkf + ((1 * 64 + lane) << 3));
    v4f c = {0.f, 0.f, 0.f, 0.f};
    c = __builtin_amdgcn_mfma_f32_16x16x32_f16(u0, b0, c, 0, 0, 0);
    c = __builtin_amdgcn_mfma_f32_16x16x32_f16(u1, b1, c, 0, 0, 0);
    if (r16 < 10) {
        float bias = bf[r16];
#pragma unroll
        for (int reg = 0; reg < 4; ++reg) {
            int node = node0 + quad * 4 + reg;
            if (node < N) out[(size_t)node * 10 + r16] = c[reg] + bias;
        }
    }
}

extern "C" void kernel_launch(void* const* d_in, const int* in_sizes, int n_in,
                              void* d_out, int out_size, void* d_ws, size_t ws_size,
                              hipStream_t stream) {
    const float* x    = (const float*)d_in[0];
    const int*   ei   = (const int*)d_in[1];
    const float* w1a  = (const float*)d_in[2];
    const float* b1a  = (const float*)d_in[3];
    const float* w1b  = (const float*)d_in[4];
    const float* b1b  = (const float*)d_in[5];
    const float* bng  = (const float*)d_in[6];
    const float* bnb  = (const float*)d_in[7];
    const float* w2a  = (const float*)d_in[8];
    const float* b2a  = (const float*)d_in[9];
    const float* w2b  = (const float*)d_in[10];
    const float* b2b  = (const float*)d_in[11];
    const float* linw = (const float*)d_in[12];
    const float* linb = (const float*)d_in[13];

    int N = in_sizes[0] / H;       // 100000
    int E = in_sizes[1] / 2;       // 1600000
    int CB = (N + CBS - 1) / CBS;  // 196 coarse buckets

    // ---- workspace layout ----
    size_t NH = (size_t)N * H;
    char*  wsb    = (char*)d_ws;
    f16*   xh     = (f16*)wsb;                           // NH fp16
    f16*   bufA   = (f16*)(wsb + NH * 2);                // NH fp16 (agg1 -> h1p in place)
    f16*   bufC   = (f16*)(wsb + NH * 4);                // NH fp16
    float* stats  = (float*)(wsb + NH * 6);              // 128
    float* scale  = stats + 128;                         // 64
    float* shiftv = stats + 192;                         // 64
    float* Wf     = stats + 256;                         // 640
    float* bf     = Wf + 640;                            // 16
    f16*   pk1a   = (f16*)(bf + 16);                     // 4096 (16B-aligned)
    f16*   pk1b   = pk1a + 4096;
    f16*   pk2a   = pk1b + 4096;
    f16*   pkf    = pk2a + 4096;                         // 1024
    int*   gcursor= (int*)(pkf + 1024);                  // 256*16
    int*   gbb    = gcursor + 256 * 16;                  // CB+1
    int*   rowptr = gbb + 257;                           // N+1
    int*   ebuf   = rowptr + (N + 1);                    // E
    int*   pairs  = ebuf + E;                            // CB*CAP slab

    int ntiles = (E + TILE - 1) / TILE;

    init_kernel<<<1, 256, 0, stream>>>(stats, gcursor, CB);
    cvt_x_kernel<<<(int)((NH / 4 + 255) / 256), 256, 0, stream>>>(x, xh, (int)(NH / 4));
    part_staged_kernel<<<ntiles, 256, 0, stream>>>(ei, gcursor, pairs, E, N, CB);
    scan_cb_kernel<<<1, 256, 0, stream>>>(gcursor, gbb, rowptr, CB, N);
    bucket_csr_kernel<<<CB, 256, 0, stream>>>(pairs, gcursor, gbb, ebuf, rowptr, N);
    fold_head_kernel<<<3, 256, 0, stream>>>(w2b, b2b, linw, linb, Wf, bf);
    repack_kernel<<<(13312 + 255) / 256, 256, 0, stream>>>(w1a, w1b, w2a, Wf,
                                                           pk1a, pk1b, pk2a, pkf);

    int gblocks = (int)(((long long)N * 64 + 255) / 256);
    int mblocks = (N + 63) / 64;
    gather1_kernel<<<gblocks, 256, 0, stream>>>(xh, rowptr, ebuf, bufA, N);
    mlp1_kernel<<<mblocks, 256, 0, stream>>>(bufA, bufA, pk1a, pk1b, b1a, b1b, stats, N);
    bn_finalize_kernel<<<1, 64, 0, stream>>>(stats, bng, bnb, scale, shiftv, (float)N);

    gather2_kernel<<<gblocks, 256, 0, stream>>>(bufA, scale, shiftv, rowptr, ebuf, bufC, N);
    mlp2_kernel<<<mblocks, 256, 0, stream>>>(bufC, pk2a, pkf, b2a, bf, (float*)d_out, N);
}

// Round 15
// 301.857 us; speedup vs baseline: 1.0420x; 1.0420x over previous
//
#include <hip/hip_runtime.h>
#include <hip/hip_fp16.h>

#define H 64
#define CBS 512           // nodes per coarse bucket
#define CB_BITS 9
#define TILE 8192         // edges per partition tile
#define CAP 9216          // slab capacity per bucket

typedef _Float16 f16;
typedef __attribute__((ext_vector_type(8))) _Float16 v8h;
typedef __attribute__((ext_vector_type(4))) float v4f;

// ---------------------------------------------------------------------------
// cvt_x + init fused: grid covers x conversion; block 0 lane 0..255 also
// zeroes BN stats and seeds slab cursors.
// ---------------------------------------------------------------------------
__global__ __launch_bounds__(256)
void cvt_init_kernel(const float* __restrict__ x, f16* __restrict__ xh, int total4,
                     float* __restrict__ stats, int* __restrict__ gcursor, int CB) {
    int i = blockIdx.x * blockDim.x + threadIdx.x;
    if (blockIdx.x == 0) {
        int t = threadIdx.x;
        if (t < 128) stats[t] = 0.f;
        if (t < CB) gcursor[t * 16] = t * CAP;
    }
    if (i >= total4) return;
    float4 v = ((const float4*)x)[i];
    f16 h0 = (f16)v.x, h1 = (f16)v.y, h2 = (f16)v.z, h3 = (f16)v.w;
    ushort4 pk;
    pk.x = *(unsigned short*)&h0; pk.y = *(unsigned short*)&h1;
    pk.z = *(unsigned short*)&h2; pk.w = *(unsigned short*)&h3;
    ((ushort4*)xh)[i] = pk;
}

// ---------------------------------------------------------------------------
// LDS-staged multi-split partition into per-bucket slabs (R11-proven).
// ---------------------------------------------------------------------------
__global__ __launch_bounds__(256)
void part_staged_kernel(const int* __restrict__ ei, int* __restrict__ gcursor,
                        int* __restrict__ pairs, int E, int N, int CB) {
    __shared__ int sd[256];
    __shared__ int excl[256];
    __shared__ int gbase[256];
    __shared__ int lcur[256];
    __shared__ int stage[TILE];
    __shared__ unsigned char bin8[TILE];
    int t = threadIdx.x;
    int ntiles = (E + TILE - 1) / TILE;
    for (int tile = blockIdx.x; tile < ntiles; tile += gridDim.x) {
        int base = tile * TILE;
        int cnt = min(TILE, E - base);
        sd[t] = 0;
        __syncthreads();
        for (int i = t; i < cnt; i += 256) {
            int s = ei[base + i];
            int d = ei[E + base + i];
            if ((unsigned)s < (unsigned)N && (unsigned)d < (unsigned)N)
                atomicAdd(&sd[d >> CB_BITS], 1);
        }
        __syncthreads();
        int v = sd[t];
        __syncthreads();
        for (int off = 1; off < 256; off <<= 1) {
            int add = (t >= off) ? sd[t - off] : 0;
            __syncthreads();
            sd[t] += add;
            __syncthreads();
        }
        int ex = sd[t] - v;
        excl[t] = ex;
        lcur[t] = ex;
        if (t < CB && v > 0) gbase[t] = atomicAdd(&gcursor[t * 16], v);
        int tot = sd[255];
        __syncthreads();
        for (int i = t; i < cnt; i += 256) {
            int s = ei[base + i];
            int d = ei[E + base + i];
            if ((unsigned)s < (unsigned)N && (unsigned)d < (unsigned)N) {
                int cb = d >> CB_BITS;
                int pos = atomicAdd(&lcur[cb], 1);
                stage[pos] = s | ((d & (CBS - 1)) << 17);
                bin8[pos] = (unsigned char)cb;
            }
        }
        __syncthreads();
        for (int i = t; i < tot; i += 256) {
            int b8 = bin8[i];
            pairs[gbase[b8] + (i - excl[b8])] = stage[i];
        }
        __syncthreads();
    }
}

__global__ __launch_bounds__(256)
void scan_cb_kernel(const int* __restrict__ gcursor, int* __restrict__ gbb,
                    int* __restrict__ rowptr, int CB, int N) {
    __shared__ int sd[256];
    int t = threadIdx.x;
    int cnt = (t < CB) ? (gcursor[t * 16] - t * CAP) : 0;
    sd[t] = cnt; __syncthreads();
    for (int off = 1; off < 256; off <<= 1) {
        int add = (t >= off) ? sd[t - off] : 0;
        __syncthreads();
        sd[t] += add;
        __syncthreads();
    }
    if (t < CB) gbb[t] = sd[t] - cnt;
    if (t == 0) { gbb[CB] = sd[255]; rowptr[N] = sd[255]; }
}

__global__ __launch_bounds__(256)
void bucket_csr_kernel(const int* __restrict__ pairs, const int* __restrict__ gcursor,
                       const int* __restrict__ gbb,
                       int* __restrict__ ebuf, int* __restrict__ rowptr, int N) {
    __shared__ int hist[CBS];
    __shared__ int cur[CBS];
    __shared__ int sd[256];
    __shared__ int carry_s;
    int b = blockIdx.x;
    int t = threadIdx.x;
    int pb = b * CAP;
    int cnt = gcursor[b * 16] - pb;
    int gb = gbb[b];
    for (int i = t; i < CBS; i += 256) hist[i] = 0;
    if (t == 0) carry_s = 0;
    __syncthreads();
    for (int i = t; i < cnt; i += 256)
        atomicAdd(&hist[(pairs[pb + i] >> 17) & (CBS - 1)], 1);
    __syncthreads();
    for (int start = 0; start < CBS; start += 256) {
        int v = hist[start + t];
        sd[t] = v; __syncthreads();
        for (int off = 1; off < 256; off <<= 1) {
            int add = (t >= off) ? sd[t - off] : 0;
            __syncthreads();
            sd[t] += add;
            __syncthreads();
        }
        int ex = sd[t] - v + carry_s;
        cur[start + t] = ex;
        int node = b * CBS + start + t;
        if (node < N) rowptr[node] = gb + ex;
        __syncthreads();
        if (t == 0) carry_s += sd[255];
        __syncthreads();
    }
    for (int i = t; i < cnt; i += 256) {
        int p = pairs[pb + i];
        int pos = atomicAdd(&cur[(p >> 17) & (CBS - 1)], 1);
        ebuf[gb + pos] = p & 0x1FFFF;
    }
}

// ---------------------------------------------------------------------------
// Repack weights into fp16 MFMA B-frag order + compute folded head inline:
//   Wf = W2b@LW (computed per-element here), bf = b2b@LW + LB.
// ---------------------------------------------------------------------------
__global__ void repack_kernel(const float* __restrict__ W1a, const float* __restrict__ W1b,
                              const float* __restrict__ W2a, const float* __restrict__ W2b,
                              const float* __restrict__ B2b, const float* __restrict__ LW,
                              const float* __restrict__ LB,
                              f16* __restrict__ pk1a, f16* __restrict__ pk1b,
                              f16* __restrict__ pk2a, f16* __restrict__ pkf,
                              float* __restrict__ bf) {
    int t = blockIdx.x * blockDim.x + threadIdx.x;
    if (t < 12288) {
        int m = t >> 12;
        int e = t & 4095;
        int j = e & 7, lane = (e >> 3) & 63, ks = (e >> 9) & 1, nt = e >> 10;
        int row = ks * 32 + ((lane >> 4) & 3) * 8 + j;
        int col = nt * 16 + (lane & 15);
        const float* W = (m == 0) ? W1a : (m == 1) ? W1b : W2a;
        f16* P = (m == 0) ? pk1a : (m == 1) ? pk1b : pk2a;
        P[e] = (f16)W[row * 64 + col];
    } else if (t < 13312) {
        int e = t - 12288;
        int j = e & 7, lane = (e >> 3) & 63, ks = e >> 9;
        int row = ks * 32 + ((lane >> 4) & 3) * 8 + j;
        int col = lane & 15;
        float a = 0.f;
        if (col < 10)
            for (int m = 0; m < H; ++m) a = fmaf(W2b[row * 64 + m], LW[m * 10 + col], a);
        pkf[e] = (f16)a;
    } else if (t < 13322) {
        int c = t - 13312;
        float a = LB[c];
        for (int m = 0; m < H; ++m) a = fmaf(B2b[m], LW[m * 10 + c], a);
        bf[c] = a;
    }
}

// ---------------------------------------------------------------------------
// Layer-1 gather (R13 shape, ILP deepened to 16): wave per node, lane=feature.
// ---------------------------------------------------------------------------
__global__ __launch_bounds__(256)
void gather1_kernel(const f16* __restrict__ xh, const int* __restrict__ rowptr,
                    const int* __restrict__ ebuf, f16* __restrict__ bufA, int N) {
    int wid = (int)(((long long)blockIdx.x * blockDim.x + threadIdx.x) >> 6);
    int lane = threadIdx.x & 63;
    if (wid >= N) return;
    int p0 = __builtin_amdgcn_readfirstlane(rowptr[wid]);
    int pe = __builtin_amdgcn_readfirstlane(rowptr[wid + 1]);
    float acc = (float)xh[((long long)wid << 6) + lane];
    int p = p0;
    for (; p + 16 <= pe; p += 16) {
        float v[16];
#pragma unroll
        for (int q = 0; q < 16; ++q)
            v[q] = (float)xh[((long long)ebuf[p + q] << 6) + lane];
        float s0 = ((v[0] + v[1]) + (v[2] + v[3])) + ((v[4] + v[5]) + (v[6] + v[7]));
        float s1 = ((v[8] + v[9]) + (v[10] + v[11])) + ((v[12] + v[13]) + (v[14] + v[15]));
        acc += s0 + s1;
    }
    if (p + 8 <= pe) {
        float v0 = (float)xh[((long long)ebuf[p + 0] << 6) + lane];
        float v1 = (float)xh[((long long)ebuf[p + 1] << 6) + lane];
        float v2 = (float)xh[((long long)ebuf[p + 2] << 6) + lane];
        float v3 = (float)xh[((long long)ebuf[p + 3] << 6) + lane];
        float v4 = (float)xh[((long long)ebuf[p + 4] << 6) + lane];
        float v5 = (float)xh[((long long)ebuf[p + 5] << 6) + lane];
        float v6 = (float)xh[((long long)ebuf[p + 6] << 6) + lane];
        float v7 = (float)xh[((long long)ebuf[p + 7] << 6) + lane];
        acc += ((v0 + v1) + (v2 + v3)) + ((v4 + v5) + (v6 + v7));
        p += 8;
    }
    for (; p < pe; ++p) acc += (float)xh[((long long)ebuf[p] << 6) + lane];
    bufA[((long long)wid << 6) + lane] = (f16)acc;
}

// ---------------------------------------------------------------------------
// Layer-2 gather (R13 shape, ILP 16) with self term and full folded BN.
// ---------------------------------------------------------------------------
__global__ __launch_bounds__(256)
void gather2_kernel(const f16* __restrict__ h1p, const float* __restrict__ scale,
                    const float* __restrict__ shiftv, const int* __restrict__ rowptr,
                    const int* __restrict__ ebuf, f16* __restrict__ bufC, int N) {
    int wid = (int)(((long long)blockIdx.x * blockDim.x + threadIdx.x) >> 6);
    int lane = threadIdx.x & 63;
    if (wid >= N) return;
    int p0 = __builtin_amdgcn_readfirstlane(rowptr[wid]);
    int pe = __builtin_amdgcn_readfirstlane(rowptr[wid + 1]);
    float acc = (float)h1p[((long long)wid << 6) + lane];   // self
    int p = p0;
    for (; p + 16 <= pe; p += 16) {
        float v[16];
#pragma unroll
        for (int q = 0; q < 16; ++q)
            v[q] = (float)h1p[((long long)ebuf[p + q] << 6) + lane];
        float s0 = ((v[0] + v[1]) + (v[2] + v[3])) + ((v[4] + v[5]) + (v[6] + v[7]));
        float s1 = ((v[8] + v[9]) + (v[10] + v[11])) + ((v[12] + v[13]) + (v[14] + v[15]));
        acc += s0 + s1;
    }
    if (p + 8 <= pe) {
        float v0 = (float)h1p[((long long)ebuf[p + 0] << 6) + lane];
        float v1 = (float)h1p[((long long)ebuf[p + 1] << 6) + lane];
        float v2 = (float)h1p[((long long)ebuf[p + 2] << 6) + lane];
        float v3 = (float)h1p[((long long)ebuf[p + 3] << 6) + lane];
        float v4 = (float)h1p[((long long)ebuf[p + 4] << 6) + lane];
        float v5 = (float)h1p[((long long)ebuf[p + 5] << 6) + lane];
        float v6 = (float)h1p[((long long)ebuf[p + 6] << 6) + lane];
        float v7 = (float)h1p[((long long)ebuf[p + 7] << 6) + lane];
        acc += ((v0 + v1) + (v2 + v3)) + ((v4 + v5) + (v6 + v7));
        p += 8;
    }
    for (; p < pe; ++p) acc += (float)h1p[((long long)ebuf[p] << 6) + lane];
    float degp1 = (float)(pe - p0 + 1);
    bufC[((long long)wid << 6) + lane] = (f16)(acc * scale[lane] + degp1 * shiftv[lane]);
}

// ---------------------------------------------------------------------------
// MFMA MLP layer 1 + fused BN stats (R13-proven).
// ---------------------------------------------------------------------------
__global__ __launch_bounds__(256)
void mlp1_kernel(const f16* __restrict__ bufA, f16* __restrict__ h1p,
                 const f16* __restrict__ pk1a, const f16* __restrict__ pk1b,
                 const float* __restrict__ B1a, const float* __restrict__ B1b,
                 float* __restrict__ stats, int N) {
    __shared__ f16 Su[4][16 * 72];
    __shared__ f16 Sh[4][16 * 72];
    __shared__ float red[2][4][64];
    int t = threadIdx.x, wv = t >> 6, lane = t & 63;
    int quad = lane >> 4, r16 = lane & 15;
    int node0 = blockIdx.x * 64 + wv * 16;
    int nodeA = node0 + r16;

    v8h a0 = {}, a1 = {};
    if (nodeA < N) {
        a0 = *(const v8h*)(bufA + (size_t)nodeA * 64 + quad * 8);
        a1 = *(const v8h*)(bufA + (size_t)nodeA * 64 + 32 + quad * 8);
    }
#pragma unroll
    for (int nt = 0; nt < 4; ++nt) {
        v8h b0 = *(const v8h*)(pk1a + (((nt * 2 + 0) * 64 + lane) << 3));
        v8h b1 = *(const v8h*)(pk1a + (((nt * 2 + 1) * 64 + lane) << 3));
        v4f c = {0.f, 0.f, 0.f, 0.f};
        c = __builtin_amdgcn_mfma_f32_16x16x32_f16(a0, b0, c, 0, 0, 0);
        c = __builtin_amdgcn_mfma_f32_16x16x32_f16(a1, b1, c, 0, 0, 0);
        float bias = B1a[nt * 16 + r16];
#pragma unroll
        for (int reg = 0; reg < 4; ++reg)
            Su[wv][(quad * 4 + reg) * 72 + nt * 16 + r16] = (f16)fmaxf(c[reg] + bias, 0.f);
    }
    __syncthreads();
    v8h u0 = *(const v8h*)(&Su[wv][r16 * 72 + quad * 8]);
    v8h u1 = *(const v8h*)(&Su[wv][r16 * 72 + 32 + quad * 8]);
#pragma unroll
    for (int nt = 0; nt < 4; ++nt) {
        v8h b0 = *(const v8h*)(pk1b + (((nt * 2 + 0) * 64 + lane) << 3));
        v8h b1 = *(const v8h*)(pk1b + (((nt * 2 + 1) * 64 + lane) << 3));
        v4f c = {0.f, 0.f, 0.f, 0.f};
        c = __builtin_amdgcn_mfma_f32_16x16x32_f16(u0, b0, c, 0, 0, 0);
        c = __builtin_amdgcn_mfma_f32_16x16x32_f16(u1, b1, c, 0, 0, 0);
        float bias = B1b[nt * 16 + r16];
#pragma unroll
        for (int reg = 0; reg < 4; ++reg) {
            int row = quad * 4 + reg;
            bool valid = (node0 + row) < N;
            Sh[wv][row * 72 + nt * 16 + r16] = valid ? (f16)(c[reg] + bias) : (f16)0;
        }
    }
    __syncthreads();
    for (int i = lane; i < 1024; i += 64) {
        int row = i >> 6, col = i & 63;
        int node = node0 + row;
        if (node < N) h1p[(size_t)node * 64 + col] = Sh[wv][row * 72 + col];
    }
    float s = 0.f, s2 = 0.f;
#pragma unroll
    for (int row = 0; row < 16; ++row) {
        float v = (float)Sh[wv][row * 72 + lane];
        s += v;
        s2 = fmaf(v, v, s2);
    }
    red[0][wv][lane] = s;
    red[1][wv][lane] = s2;
    __syncthreads();
    if (wv == 0) {
        float ts  = (red[0][0][lane] + red[0][1][lane]) + (red[0][2][lane] + red[0][3][lane]);
        float ts2 = (red[1][0][lane] + red[1][1][lane]) + (red[1][2][lane] + red[1][3][lane]);
        unsafeAtomicAdd(&stats[lane], ts);
        unsafeAtomicAdd(&stats[64 + lane], ts2);
    }
}

__global__ void bn_finalize_kernel(const float* __restrict__ stats,
                                   const float* __restrict__ gamma,
                                   const float* __restrict__ beta,
                                   float* __restrict__ scale, float* __restrict__ shiftv, float n) {
    int f = threadIdx.x;
    if (f >= H) return;
    float mean = stats[f] / n;
    float var = stats[H + f] / n - mean * mean;   // biased, matches jnp.var
    var = fmaxf(var, 0.f);
    float s = gamma[f] * rsqrtf(var + 1e-5f);
    scale[f] = s;
    shiftv[f] = beta[f] - mean * s;
}

// ---------------------------------------------------------------------------
// MFMA MLP layer 2 + folded head (R13-proven).
// ---------------------------------------------------------------------------
__global__ __launch_bounds__(256)
void mlp2_kernel(const f16* __restrict__ bufC,
                 const f16* __restrict__ pk2a, const f16* __restrict__ pkf,
                 const float* __restrict__ B2a, const float* __restrict__ bf,
                 float* __restrict__ out, int N) {
    __shared__ f16 Su[4][16 * 72];
    int t = threadIdx.x, wv = t >> 6, lane = t & 63;
    int quad = lane >> 4, r16 = lane & 15;
    int node0 = blockIdx.x * 64 + wv * 16;
    int nodeA = node0 + r16;

    v8h a0 = {}, a1 = {};
    if (nodeA < N) {
        a0 = *(const v8h*)(bufC + (size_t)nodeA * 64 + quad * 8);
        a1 = *(const v8h*)(bufC + (size_t)nodeA * 64 + 32 + quad * 8);
    }
#pragma unroll
    for (int nt = 0; nt < 4; ++nt) {
        v8h b0 = *(const v8h*)(pk2a + (((nt * 2 + 0) * 64 + lane) << 3));
        v8h b1 = *(const v8h*)(pk2a + (((nt * 2 + 1) * 64 + lane) << 3));
        v4f c = {0.f, 0.f, 0.f, 0.f};
        c = __builtin_amdgcn_mfma_f32_16x16x32_f16(a0, b0, c, 0, 0, 0);
        c = __builtin_amdgcn_mfma_f32_16x16x32_f16(a1, b1, c, 0, 0, 0);
        float bias = B2a[nt * 16 + r16];
#pragma unroll
        for (int reg = 0; reg < 4; ++reg)
            Su[wv][(quad * 4 + reg) * 72 + nt * 16 + r16] = (f16)fmaxf(c[reg] + bias, 0.f);
    }
    __syncthreads();
    v8h u0 = *(const v8h*)(&Su[wv][r16 * 72 + quad * 8]);
    v8h u1 = *(const v8h*)(&Su[wv][r16 * 72 + 32 + quad * 8]);
    v8h b0 = *(const v8h*)(pkf + ((0 * 64 + lane) << 3));
    v8h b1 = *(const v8h*)(pkf + ((1 * 64 + lane) << 3));
    v4f c = {0.f, 0.f, 0.f, 0.f};
    c = __builtin_amdgcn_mfma_f32_16x16x32_f16(u0, b0, c, 0, 0, 0);
    c = __builtin_amdgcn_mfma_f32_16x16x32_f16(u1, b1, c, 0, 0, 0);
    if (r16 < 10) {
        float bias = bf[r16];
#pragma unroll
        for (int reg = 0; reg < 4; ++reg) {
            int node = node0 + quad * 4 + reg;
            if (node < N) out[(size_t)node * 10 + r16] = c[reg] + bias;
        }
    }
}

extern "C" void kernel_launch(void* const* d_in, const int* in_sizes, int n_in,
                              void* d_out, int out_size, void* d_ws, size_t ws_size,
                              hipStream_t stream) {
    const float* x    = (const float*)d_in[0];
    const int*   ei   = (const int*)d_in[1];
    const float* w1a  = (const float*)d_in[2];
    const float* b1a  = (const float*)d_in[3];
    const float* w1b  = (const float*)d_in[4];
    const float* b1b  = (const float*)d_in[5];
    const float* bng  = (const float*)d_in[6];
    const float* bnb  = (const float*)d_in[7];
    const float* w2a  = (const float*)d_in[8];
    const float* b2a  = (const float*)d_in[9];
    const float* w2b  = (const float*)d_in[10];
    const float* b2b  = (const float*)d_in[11];
    const float* linw = (const float*)d_in[12];
    const float* linb = (const float*)d_in[13];

    int N = in_sizes[0] / H;       // 100000
    int E = in_sizes[1] / 2;       // 1600000
    int CB = (N + CBS - 1) / CBS;  // 196 coarse buckets

    // ---- workspace layout ----
    size_t NH = (size_t)N * H;
    char*  wsb    = (char*)d_ws;
    f16*   xh     = (f16*)wsb;                           // NH fp16
    f16*   bufA   = (f16*)(wsb + NH * 2);                // NH fp16 (agg1 -> h1p in place)
    f16*   bufC   = (f16*)(wsb + NH * 4);                // NH fp16
    float* stats  = (float*)(wsb + NH * 6);              // 128
    float* scale  = stats + 128;                         // 64
    float* shiftv = stats + 192;                         // 64
    float* bf     = stats + 256;                         // 16
    f16*   pk1a   = (f16*)(bf + 16);                     // 4096 (16B-aligned)
    f16*   pk1b   = pk1a + 4096;
    f16*   pk2a   = pk1b + 4096;
    f16*   pkf    = pk2a + 4096;                         // 1024
    int*   gcursor= (int*)(pkf + 1024);                  // 256*16
    int*   gbb    = gcursor + 256 * 16;                  // CB+1
    int*   rowptr = gbb + 257;                           // N+1
    int*   ebuf   = rowptr + (N + 1);                    // E
    int*   pairs  = ebuf + E;                            // CB*CAP slab

    int ntiles = (E + TILE - 1) / TILE;

    cvt_init_kernel<<<(int)((NH / 4 + 255) / 256), 256, 0, stream>>>(
        x, xh, (int)(NH / 4), stats, gcursor, CB);
    part_staged_kernel<<<ntiles, 256, 0, stream>>>(ei, gcursor, pairs, E, N, CB);
    scan_cb_kernel<<<1, 256, 0, stream>>>(gcursor, gbb, rowptr, CB, N);
    bucket_csr_kernel<<<CB, 256, 0, stream>>>(pairs, gcursor, gbb, ebuf, rowptr, N);
    repack_kernel<<<(13322 + 255) / 256, 256, 0, stream>>>(
        w1a, w1b, w2a, w2b, b2b, linw, linb, pk1a, pk1b, pk2a, pkf, bf);

    int gblocks = (int)(((long long)N * 64 + 255) / 256);
    int mblocks = (N + 63) / 64;
    gather1_kernel<<<gblocks, 256, 0, stream>>>(xh, rowptr, ebuf, bufA, N);
    mlp1_kernel<<<mblocks, 256, 0, stream>>>(bufA, bufA, pk1a, pk1b, b1a, b1b, stats, N);
    bn_finalize_kernel<<<1, 64, 0, stream>>>(stats, bng, bnb, scale, shiftv, (float)N);

    gather2_kernel<<<gblocks, 256, 0, stream>>>(bufA, scale, shiftv, rowptr, ebuf, bufC, N);
    mlp2_kernel<<<mblocks, 256, 0, stream>>>(bufC, pk2a, pkf, b2a, bf, (float*)d_out, N);
}